// Round 13
// baseline (140.541 us; speedup 1.0000x reference)
//
#include <hip/hip_runtime.h>

// Problem constants
#define BSZ 16
#define NN  128
#define HH  256
#define LLG 9
#define FFE 48   // edge feature dim (padded to 64 for MFMA K)

typedef float        f32x4 __attribute__((ext_vector_type(4)));
typedef _Float16     f16x8 __attribute__((ext_vector_type(8)));
typedef unsigned int u32x4 __attribute__((ext_vector_type(4)));

static __device__ __forceinline__ unsigned short f2h_bits(float x) {
    _Float16 h = (_Float16)x;   // RNE
    return __builtin_bit_cast(unsigned short, h);
}

static __device__ __forceinline__ float fast_silu(float x) {
    float e = __builtin_amdgcn_exp2f(x * -1.44269504088896341f);
    return x * __builtin_amdgcn_rcpf(1.0f + e);
}

// ---------------------------------------------------------------------------
// Kernel 1: weight transpose + f32->f16 convert.  (proven, R12 verbatim)
// ---------------------------------------------------------------------------
__global__ __launch_bounds__(256) void pre_w(
    const float* __restrict__ W1, const float* __restrict__ W2,
    unsigned short* __restrict__ W2T, unsigned short* __restrict__ WeT)
{
    int tid = blockIdx.x * 256 + threadIdx.x;   // grid 256 -> 65536 threads
    {
        int ho = tid >> 8, k = tid & 255;
        W2T[(ho << 8) + k] = f2h_bits(W2[(k << 8) + ho]);  // coalesced write
    }
    if (tid < 256 * 64) {
        int h = tid >> 6, f = tid & 63;
        WeT[(h << 6) + f] = (f < FFE) ? f2h_bits(W1[(521 + f) * HH + h])
                                      : (unsigned short)0;
    }
}

// ---------------------------------------------------------------------------
// Kernel 2: pj/base precompute — 512-block / 4-rows version (proven fastest).
// ---------------------------------------------------------------------------
__global__ __launch_bounds__(256) void pre_pjbase(
    const float* __restrict__ node, const float* __restrict__ graph,
    const float* __restrict__ W1, const float* __restrict__ b1,
    float* __restrict__ pj, float* __restrict__ base)
{
    __shared__ float nrow[4][HH];
    __shared__ float gsh[LLG];
    const int blk = blockIdx.x;
    const int b = blk >> 5;             // 32 row-groups of 4 per batch
    const int r0 = (blk & 31) << 2;
    const int h = threadIdx.x;

    for (int t = h; t < 4 * HH; t += 256) {
        int r = t >> 8, k = t & 255;
        nrow[r][k] = node[(((size_t)b * NN) + r0 + r) * HH + k];
    }
    if (h < LLG) gsh[h] = graph[b * LLG + h];
    __syncthreads();

    float accj[4] = {0,0,0,0};
    float acci[4] = {0,0,0,0};
    for (int k = 0; k < HH; ++k) {
        float wj = W1[k * HH + h];
        float wi = W1[(k + HH) * HH + h];
        #pragma unroll
        for (int r = 0; r < 4; ++r) {
            float nv = nrow[r][k];
            accj[r] = fmaf(nv, wj, accj[r]);
            acci[r] = fmaf(nv, wi, acci[r]);
        }
    }
    float accg = b1[h];
    #pragma unroll
    for (int l = 0; l < LLG; ++l)
        accg = fmaf(gsh[l], W1[(2 * HH + l) * HH + h], accg);

    #pragma unroll
    for (int r = 0; r < 4; ++r) {
        size_t off = (((size_t)b * NN) + r0 + r) * HH + h;
        pj[off]   = accj[r];
        base[off] = acci[r] + accg;
    }
}

// ---------------------------------------------------------------------------
// Kernel 3: fused main — HALF-BLOCK variant. Grid 4096: block = (bi, j-half).
// Each 256-thread block owns 64 j-rows end-to-end:
//   stage efs(8 KB, own j-half); bar; GEMM1 (wave h-slice 64, acc1[4][4]);
//   epi1 -> h1s(32 KB, own j-half x all h); bar;
//   GEMM2 (wave ho-slice 64, acc2[4][4], 16 MFMA / 8 loads ILP);
//   epi2 silu + j-half sum -> part[half][bi][ho].
// vs R5: SAME MFMA/VALU totals & occupancy (16 waves/CU), but h1 A-read
// traffic HALVED (4 waves x 32 KB x 2 vs 8 x 64 KB), 4-wave barriers,
// 4 desynced blocks/CU. Tests whether the ~22 us LDS pipe was critical.
// ---------------------------------------------------------------------------
__global__ __launch_bounds__(256, 4) void fused_half(
    const float* __restrict__ edge, const float* __restrict__ pj,
    const float* __restrict__ base, const unsigned short* __restrict__ W2T,
    const unsigned short* __restrict__ WeT, const float* __restrict__ b2,
    float* __restrict__ part)
{
    __shared__ unsigned char h1s[64 * HH * 2];   // 32 KB: h1[jc][h], swizzled
    __shared__ unsigned char efs[64 * 64 * 2];   //  8 KB: edge[jc][f], padded+swizzled
    const int tid  = threadIdx.x;
    const int w    = tid >> 6;         // wave 0..3
    const int lane = tid & 63;
    const int q    = lane >> 4;        // quad 0..3
    const int c    = lane & 15;
    // T1 swizzle: 4096 blocks, 8 XCDs; consecutive (bi,half) pairs same XCD
    const int g    = blockIdx.x;
    const int gid  = ((g & 7) << 9) + (g >> 3);
    const int bi   = gid >> 1;         // b*128 + i
    const int half = gid & 1;          // j-half
    const int b    = bi >> 7;

    const float* eb = edge + (size_t)bi * (NN * FFE) + half * (64 * FFE);

    // ---- stage 64 edge rows -> f16 LDS (768 float4 over 256 threads) ----
    #pragma unroll
    for (int p = 0; p < 3; ++p) {
        const int e4 = p * 256 + tid;            // float4 index, < 768
        const int j  = e4 / 12;                  // 12 float4 per 48-float row
        const int f4 = e4 - j * 12;              // 0..11
        const f32x4 x = *reinterpret_cast<const f32x4*>(eb + (e4 << 2));
        unsigned int lo = __builtin_bit_cast(unsigned int,
                            __builtin_amdgcn_cvt_pkrtz(x[0], x[1]));
        unsigned int hi = __builtin_bit_cast(unsigned int,
                            __builtin_amdgcn_cvt_pkrtz(x[2], x[3]));
        const unsigned int off = (unsigned)(j << 7) +
            (((unsigned)(f4 << 3)) ^ ((unsigned)(j & 7) << 4));
        *reinterpret_cast<uint2*>(&efs[off]) = make_uint2(lo, hi);
    }
    {   // zero-fill padded f in [48,64): 64 rows x 4 uint2 = 256
        const int j = tid >> 2, gg = tid & 3;
        const unsigned int off = (unsigned)(j << 7) +
            (((unsigned)(96 + (gg << 3))) ^ ((unsigned)(j & 7) << 4));
        *reinterpret_cast<uint2*>(&efs[off]) = make_uint2(0u, 0u);
    }
    __syncthreads();   // bar1: efs ready (4-wave)

    // ------------------ GEMM1: D1[h(64), jc(64)] ------------------
    f32x4 acc1[4][4];
    #pragma unroll
    for (int mt = 0; mt < 4; ++mt)
        #pragma unroll
        for (int nt = 0; nt < 4; ++nt) acc1[mt][nt] = f32x4{0.f, 0.f, 0.f, 0.f};

    #pragma unroll
    for (int kk = 0; kk < 2; ++kk) {
        const int koff = (kk << 5) + (q << 3);   // f16-units f offset
        const int fb   = koff << 1;              // byte offset in efs row
        f16x8 af[4];
        #pragma unroll
        for (int mt = 0; mt < 4; ++mt) {
            const int row = (w << 6) + (mt << 4) + c;       // h
            af[mt] = *reinterpret_cast<const f16x8*>(WeT + (row << 6) + koff);
        }
        #pragma unroll
        for (int nt = 0; nt < 4; ++nt) {
            const int j = (nt << 4) + c;                    // local jc
            const f16x8 bf = *reinterpret_cast<const f16x8*>(
                &efs[(unsigned)(j << 7) +
                     (((unsigned)fb) ^ ((unsigned)(j & 7) << 4))]);
            #pragma unroll
            for (int mt = 0; mt < 4; ++mt)
                acc1[mt][nt] = __builtin_amdgcn_mfma_f32_16x16x32_f16(
                    af[mt], bf, acc1[mt][nt], 0, 0, 0);
        }
    }

    // epilogue 1: z1 -> silu -> f16 -> h1s (swizzle: byte ^= (jc&7)<<4)
    #pragma unroll
    for (int mt = 0; mt < 4; ++mt) {
        const int h0 = (w << 6) + (mt << 4) + (q << 2);
        const f32x4 bb = *reinterpret_cast<const f32x4*>(
            base + ((size_t)bi << 8) + h0);
        #pragma unroll
        for (int nt = 0; nt < 4; ++nt) {
            const int jc = (nt << 4) + c;
            const int jg = (half << 6) + jc;
            const f32x4 pjv = *reinterpret_cast<const f32x4*>(
                pj + (((size_t)b << 7) + jg) * HH + h0);
            float s0 = fast_silu(acc1[mt][nt][0] + bb[0] + pjv[0]);
            float s1 = fast_silu(acc1[mt][nt][1] + bb[1] + pjv[1]);
            float s2 = fast_silu(acc1[mt][nt][2] + bb[2] + pjv[2]);
            float s3 = fast_silu(acc1[mt][nt][3] + bb[3] + pjv[3]);
            unsigned int lo = __builtin_bit_cast(unsigned int,
                                __builtin_amdgcn_cvt_pkrtz(s0, s1));
            unsigned int hi = __builtin_bit_cast(unsigned int,
                                __builtin_amdgcn_cvt_pkrtz(s2, s3));
            const unsigned int off = (unsigned)(jc << 9) +
                (((unsigned)(h0 << 1)) ^ ((unsigned)(jc & 7) << 4));
            *reinterpret_cast<uint2*>(&h1s[off]) = make_uint2(lo, hi);
        }
    }
    __syncthreads();   // bar2: h1s ready (4-wave)

    // ------------------ GEMM2: D2[jc(64), ho(64)] ------------------
    f32x4 acc2[4][4];
    #pragma unroll
    for (int m = 0; m < 4; ++m)
        #pragma unroll
        for (int nt = 0; nt < 4; ++nt) acc2[m][nt] = f32x4{0.f, 0.f, 0.f, 0.f};

    #pragma unroll 2
    for (int kk = 0; kk < 8; ++kk) {
        const int kb = (kk << 6) + (q << 4);     // byte offset of k-slice
        f16x8 bw[4];
        #pragma unroll
        for (int nt = 0; nt < 4; ++nt) {
            const int ho = (w << 6) + (nt << 4) + c;
            bw[nt] = *reinterpret_cast<const f16x8*>(
                W2T + (ho << 8) + (kk << 5) + (q << 3));
        }
        f16x8 a2[4];
        #pragma unroll
        for (int m = 0; m < 4; ++m) {
            const int jc = (m << 4) + c;
            const unsigned int off = (unsigned)(jc << 9) +
                (((unsigned)kb) ^ ((unsigned)(jc & 7) << 4));
            a2[m] = *reinterpret_cast<const f16x8*>(&h1s[off]);
        }
        #pragma unroll
        for (int m = 0; m < 4; ++m)
            #pragma unroll
            for (int nt = 0; nt < 4; ++nt)
                acc2[m][nt] = __builtin_amdgcn_mfma_f32_16x16x32_f16(
                    a2[m], bw[nt], acc2[m][nt], 0, 0, 0);
    }

    // epilogue 2: silu + j-half sum, butterfly across quads, store partial
    float s[4] = {0.f, 0.f, 0.f, 0.f};
    #pragma unroll
    for (int nt = 0; nt < 4; ++nt) {
        const float b2v = b2[(w << 6) + (nt << 4) + c];
        #pragma unroll
        for (int m = 0; m < 4; ++m)
            #pragma unroll
            for (int r = 0; r < 4; ++r)
                s[nt] += fast_silu(acc2[m][nt][r] + b2v);
    }
    #pragma unroll
    for (int nt = 0; nt < 4; ++nt) {
        s[nt] += __shfl_xor(s[nt], 16);
        s[nt] += __shfl_xor(s[nt], 32);
    }
    const float v = (q == 0) ? s[0] : (q == 1) ? s[1] : (q == 2) ? s[2] : s[3];
    part[((size_t)half << 19) + ((size_t)bi << 8) + (w << 6) + lane] = v;
}

// ---------------------------------------------------------------------------
// Kernel 4: combine halves: out = (p0 + p1) / 128   (512K elements)
// ---------------------------------------------------------------------------
__global__ __launch_bounds__(256) void combine(
    const float* __restrict__ part, float* __restrict__ out)
{
    const int i = blockIdx.x * 256 + threadIdx.x;   // grid 2048
    out[i] = (part[i] + part[(1 << 19) + i]) * 0.0078125f;
}

// ---------------------------------------------------------------------------
extern "C" void kernel_launch(void* const* d_in, const int* in_sizes, int n_in,
                              void* d_out, int out_size, void* d_ws, size_t ws_size,
                              hipStream_t stream)
{
    const float* node  = (const float*)d_in[0];
    const float* edge  = (const float*)d_in[1];
    const float* graph = (const float*)d_in[2];
    const float* W1    = (const float*)d_in[3];
    const float* b1    = (const float*)d_in[4];
    const float* W2    = (const float*)d_in[5];
    const float* b2    = (const float*)d_in[6];
    float* out = (float*)d_out;

    char* ws = (char*)d_ws;
    unsigned short* W2T = (unsigned short*)ws;              // 131072 B
    unsigned short* WeT = (unsigned short*)(ws + 131072);   //  32768 B
    float* pj   = (float*)(ws + 163840);                    // 2 MB
    float* base = (float*)(ws + 163840 + 2097152);          // 2 MB
    float* part = (float*)(ws + 163840 + 2097152 + 2097152); // 4 MB (2 halves)

    pre_w     <<<256, 256, 0, stream>>>(W1, W2, W2T, WeT);
    pre_pjbase<<<512, 256, 0, stream>>>(node, graph, W1, b1, pj, base);
    fused_half<<<2 * BSZ * NN, 256, 0, stream>>>(edge, pj, base, W2T, WeT, b2, part);
    combine   <<<2048, 256, 0, stream>>>(part, out);
}

// Round 14
// 100.073 us; speedup vs baseline: 1.4044x; 1.4044x over previous
//
#include <hip/hip_runtime.h>

// Problem constants
#define BSZ 16
#define NN  128
#define HH  256
#define LLG 9
#define FFE 48   // edge feature dim (padded to 64 for MFMA K)

typedef float        f32x4 __attribute__((ext_vector_type(4)));
typedef _Float16     f16x8 __attribute__((ext_vector_type(8)));
typedef unsigned int u32x4 __attribute__((ext_vector_type(4)));

static __device__ __forceinline__ unsigned short f2h_bits(float x) {
    _Float16 h = (_Float16)x;   // RNE
    return __builtin_bit_cast(unsigned short, h);
}

static __device__ __forceinline__ float fast_silu(float x) {
    float e = __builtin_amdgcn_exp2f(x * -1.44269504088896341f);
    return x * __builtin_amdgcn_rcpf(1.0f + e);
}

// ---------------------------------------------------------------------------
// Kernel 1: weight prep. Grid 784.
//   blk 0..255 : W2T[ho][k] (256x256 f16)  + WeT[h][f] (256x64 f16, padded)
//   blk 256..767: W1jiT[h'][f] (512x256 f16) = W1[f + 256*(h'>=256)][h'&255]
//   blk 768..783: pg[b][h] = b1[h] + graph[b]@Wg   (16x256 f32)
// ---------------------------------------------------------------------------
__global__ __launch_bounds__(256) void pre_w(
    const float* __restrict__ W1, const float* __restrict__ W2,
    const float* __restrict__ graph, const float* __restrict__ b1,
    unsigned short* __restrict__ W2T, unsigned short* __restrict__ WeT,
    unsigned short* __restrict__ W1jiT, float* __restrict__ pg)
{
    const int blk = blockIdx.x;
    const int t   = threadIdx.x;
    if (blk < 256) {
        int tid = blk * 256 + t;
        int ho = tid >> 8, k = tid & 255;
        W2T[(ho << 8) + k] = f2h_bits(W2[(k << 8) + ho]);
        if (tid < 256 * 64) {
            int h = tid >> 6, f = tid & 63;
            WeT[(h << 6) + f] = (f < FFE) ? f2h_bits(W1[(521 + f) * HH + h])
                                          : (unsigned short)0;
        }
    } else if (blk < 768) {
        int tid = (blk - 256) * 256 + t;      // 0..131071
        int hp = tid >> 8, f = tid & 255;     // h' 0..511, f 0..255
        int src = (((hp >> 8) << 8) + f) * HH + (hp & 255);
        W1jiT[(hp << 8) + f] = f2h_bits(W1[src]);
    } else {
        int b = blk - 768;                    // 0..15
        float acc = b1[t];
        #pragma unroll
        for (int l = 0; l < LLG; ++l)
            acc = fmaf(graph[b * LLG + l], W1[(2 * HH + l) * HH + t], acc);
        pg[(b << 8) + t] = acc;
    }
}

// ---------------------------------------------------------------------------
// Kernel 2: pj/base via MFMA. Grid 64 = (b, r-quarter). 4 waves.
//   D[h'(512), r(32)] = sum_f W1jiT[h'][f] * node[b][r0+r][f]   (K=256)
//   wave w owns h'-slice [w*128, w*128+128): w<2 -> pj, w>=2 -> base(+pg).
// Replaces the vector version (~8-9 us, 256 MB L2 W1 stream, grid-starved)
// with 128 MFMA/wave + 16 MB L2 traffic.
// ---------------------------------------------------------------------------
__global__ __launch_bounds__(256) void pre_pjbase_mfma(
    const float* __restrict__ node, const unsigned short* __restrict__ W1jiT,
    const float* __restrict__ pg,
    float* __restrict__ pj, float* __restrict__ base)
{
    __shared__ unsigned char nls[32 * 512];   // 16 KB: node[r][f] f16, swizzled
    const int tid = threadIdx.x;
    const int w    = tid >> 6;
    const int lane = tid & 63;
    const int q    = lane >> 4;
    const int c    = lane & 15;
    const int b  = blockIdx.x >> 2;
    const int r0 = (blockIdx.x & 3) << 5;
    const unsigned ck = (unsigned)(c & 7) << 4;

    // stage node rows r0..r0+32 (32x256 f32 -> f16), swizzled rows of 512 B
    const float* nb = node + (((size_t)b << 7) + r0) * HH;
    #pragma unroll
    for (int p = 0; p < 8; ++p) {
        const int e4 = (p << 8) + tid;        // float4 idx < 2048
        const int r  = e4 >> 6, f4 = e4 & 63;
        const f32x4 x = *reinterpret_cast<const f32x4*>(nb + (e4 << 2));
        unsigned int lo = __builtin_bit_cast(unsigned int,
                            __builtin_amdgcn_cvt_pkrtz(x[0], x[1]));
        unsigned int hi = __builtin_bit_cast(unsigned int,
                            __builtin_amdgcn_cvt_pkrtz(x[2], x[3]));
        const unsigned off = (unsigned)(r << 9) +
            (((unsigned)(f4 << 3)) ^ ((unsigned)(r & 7) << 4));
        *reinterpret_cast<uint2*>(&nls[off]) = make_uint2(lo, hi);
    }
    __syncthreads();

    const int wh = w << 7;                    // h'-slice base
    f32x4 acc[8][2];
    #pragma unroll
    for (int mt = 0; mt < 8; ++mt)
        #pragma unroll
        for (int nt = 0; nt < 2; ++nt) acc[mt][nt] = f32x4{0.f, 0.f, 0.f, 0.f};

    #pragma unroll 2
    for (int kk = 0; kk < 8; ++kk) {
        const unsigned kb = (unsigned)((kk << 6) + (q << 4));
        f16x8 bfr[2];
        #pragma unroll
        for (int nt = 0; nt < 2; ++nt) {
            const int r = (nt << 4) + c;
            bfr[nt] = *reinterpret_cast<const f16x8*>(
                &nls[(unsigned)(r << 9) + (kb ^ ck)]);
        }
        #pragma unroll
        for (int mt = 0; mt < 8; ++mt) {
            const f16x8 af = *reinterpret_cast<const f16x8*>(
                W1jiT + ((wh + (mt << 4) + c) << 8) + (kk << 5) + (q << 3));
            #pragma unroll
            for (int nt = 0; nt < 2; ++nt)
                acc[mt][nt] = __builtin_amdgcn_mfma_f32_16x16x32_f16(
                    af, bfr[nt], acc[mt][nt], 0, 0, 0);
        }
    }

    // epilogue: D rows h' = wh + mt*16 + q*4 + j ; cols r = nt*16 + c
    if (w < 2) {
        #pragma unroll
        for (int mt = 0; mt < 8; ++mt) {
            const int hb = wh + (mt << 4) + (q << 2);
            #pragma unroll
            for (int nt = 0; nt < 2; ++nt) {
                const int r = r0 + (nt << 4) + c;
                *reinterpret_cast<f32x4*>(
                    pj + (((size_t)b << 7) + r) * HH + hb) = acc[mt][nt];
            }
        }
    } else {
        #pragma unroll
        for (int mt = 0; mt < 8; ++mt) {
            const int hb = wh - 256 + (mt << 4) + (q << 2);
            const f32x4 pgv = *reinterpret_cast<const f32x4*>(
                pg + (b << 8) + hb);
            #pragma unroll
            for (int nt = 0; nt < 2; ++nt) {
                const int r = r0 + (nt << 4) + c;
                *reinterpret_cast<f32x4*>(
                    base + (((size_t)b << 7) + r) * HH + hb) = acc[mt][nt] + pgv;
            }
        }
    }
}

// ---------------------------------------------------------------------------
// Kernel 3: fused main — R12 VERBATIM (best: 92 us fused; R5 structure + T1
// XCD-chunked swizzle). 7 structural variants all regressed; do not touch.
// ---------------------------------------------------------------------------
__global__ __launch_bounds__(512, 4) void fused_msg(
    const float* __restrict__ edge, const float* __restrict__ pj,
    const float* __restrict__ base, const unsigned short* __restrict__ W2T,
    const unsigned short* __restrict__ WeT, const float* __restrict__ b2,
    float* __restrict__ out)
{
    __shared__ unsigned char h1s[NN * HH * 2];   // 64 KB: h1[j][h] f16, swizzled
    __shared__ unsigned char efs[NN * 64 * 2];   // 16 KB: edge[j][f] f16, padded+swizzled
    const int tid  = threadIdx.x;
    const int w    = tid >> 6;         // wave 0..7
    const int lane = tid & 63;
    const int q    = lane >> 4;        // quad 0..3
    const int c    = lane & 15;
    // T1: XCD-chunked swizzle (2048 blocks, 8 XCDs, 2048%8==0 -> bijective)
    const int g    = blockIdx.x;
    const int bi   = ((g & 7) << 8) + (g >> 3);   // b*128 + i
    const int b    = bi >> 7;

    const float* eb = edge + (size_t)bi * (NN * FFE);

    // ---- stage edge block -> f16 LDS, row-padded to 64 f16, XOR-swizzled ----
    #pragma unroll
    for (int p = 0; p < 3; ++p) {
        const int e4 = p * 512 + tid;            // float4 index, < 1536
        const int j  = e4 / 12;                  // 12 float4 per 48-float row
        const int f4 = e4 - j * 12;              // 0..11
        const f32x4 x = *reinterpret_cast<const f32x4*>(eb + (e4 << 2));
        unsigned int lo = __builtin_bit_cast(unsigned int,
                            __builtin_amdgcn_cvt_pkrtz(x[0], x[1]));
        unsigned int hi = __builtin_bit_cast(unsigned int,
                            __builtin_amdgcn_cvt_pkrtz(x[2], x[3]));
        const unsigned int off = (unsigned)(j << 7) +
            (((unsigned)(f4 << 3)) ^ ((unsigned)(j & 7) << 4));
        *reinterpret_cast<uint2*>(&efs[off]) = make_uint2(lo, hi);
    }
    {   // zero-fill padded f in [48,64)
        const int j = tid >> 2, gg = tid & 3;
        const unsigned int off = (unsigned)(j << 7) +
            (((unsigned)(96 + (gg << 3))) ^ ((unsigned)(j & 7) << 4));
        *reinterpret_cast<uint2*>(&efs[off]) = make_uint2(0u, 0u);
    }
    __syncthreads();

    // ------------------ GEMM1: D1[h(32), j(128)] ------------------
    f32x4 acc1[2][8];
    #pragma unroll
    for (int mt = 0; mt < 2; ++mt)
        #pragma unroll
        for (int nt = 0; nt < 8; ++nt) acc1[mt][nt] = f32x4{0.f, 0.f, 0.f, 0.f};

    #pragma unroll
    for (int kk = 0; kk < 2; ++kk) {
        const int koff = (kk << 5) + (q << 3);   // f16-units f offset
        const int fb   = koff << 1;              // byte offset in efs row
        f16x8 af[2];
        #pragma unroll
        for (int mt = 0; mt < 2; ++mt) {
            const int row = (w << 5) + (mt << 4) + c;       // h
            af[mt] = *reinterpret_cast<const f16x8*>(WeT + (row << 6) + koff);
        }
        #pragma unroll
        for (int nt = 0; nt < 8; ++nt) {
            const int j = (nt << 4) + c;
            const f16x8 bf = *reinterpret_cast<const f16x8*>(
                &efs[(unsigned)(j << 7) +
                     (((unsigned)fb) ^ ((unsigned)(j & 7) << 4))]);
            #pragma unroll
            for (int mt = 0; mt < 2; ++mt)
                acc1[mt][nt] = __builtin_amdgcn_mfma_f32_16x16x32_f16(
                    af[mt], bf, acc1[mt][nt], 0, 0, 0);
        }
    }

    // epilogue 1: z1 -> silu -> f16 -> h1s (swizzle: byte ^= (j&7)<<4)
    #pragma unroll
    for (int mt = 0; mt < 2; ++mt) {
        const int h0 = (w << 5) + (mt << 4) + (q << 2);
        const f32x4 bb = *reinterpret_cast<const f32x4*>(
            base + ((size_t)bi << 8) + h0);
        #pragma unroll
        for (int nt = 0; nt < 8; ++nt) {
            const int jc = (nt << 4) + c;
            const f32x4 pjv = *reinterpret_cast<const f32x4*>(
                pj + (((size_t)b << 7) + jc) * HH + h0);
            float s0 = fast_silu(acc1[mt][nt][0] + bb[0] + pjv[0]);
            float s1 = fast_silu(acc1[mt][nt][1] + bb[1] + pjv[1]);
            float s2 = fast_silu(acc1[mt][nt][2] + bb[2] + pjv[2]);
            float s3 = fast_silu(acc1[mt][nt][3] + bb[3] + pjv[3]);
            unsigned int lo = __builtin_bit_cast(unsigned int,
                                __builtin_amdgcn_cvt_pkrtz(s0, s1));
            unsigned int hi = __builtin_bit_cast(unsigned int,
                                __builtin_amdgcn_cvt_pkrtz(s2, s3));
            const unsigned int off = (unsigned)(jc << 9) +
                (((unsigned)(h0 << 1)) ^ ((unsigned)(jc & 7) << 4));
            *reinterpret_cast<uint2*>(&h1s[off]) = make_uint2(lo, hi);
        }
    }
    __syncthreads();

    // ------------------ GEMM2: D2[jc(128), ho(32)] ------------------
    f32x4 acc2[8][2];
    #pragma unroll
    for (int mt = 0; mt < 8; ++mt)
        #pragma unroll
        for (int nt = 0; nt < 2; ++nt) acc2[mt][nt] = f32x4{0.f, 0.f, 0.f, 0.f};

    #pragma unroll 2
    for (int kk = 0; kk < 8; ++kk) {
        const int kb = (kk << 6) + (q << 4);     // byte offset of k-slice
        f16x8 bw[2];
        #pragma unroll
        for (int nt = 0; nt < 2; ++nt) {
            const int ho = (w << 5) + (nt << 4) + c;
            bw[nt] = *reinterpret_cast<const f16x8*>(
                W2T + (ho << 8) + (kk << 5) + (q << 3));
        }
        #pragma unroll
        for (int gg = 0; gg < 2; ++gg) {
            f16x8 a2[4];
            #pragma unroll
            for (int m = 0; m < 4; ++m) {
                const int jc = ((gg << 2) + m) * 16 + c;
                const unsigned int off = (unsigned)(jc << 9) +
                    (((unsigned)kb) ^ ((unsigned)(jc & 7) << 4));
                a2[m] = *reinterpret_cast<const f16x8*>(&h1s[off]);
            }
            #pragma unroll
            for (int m = 0; m < 4; ++m)
                #pragma unroll
                for (int nt = 0; nt < 2; ++nt)
                    acc2[(gg << 2) + m][nt] = __builtin_amdgcn_mfma_f32_16x16x32_f16(
                        a2[m], bw[nt], acc2[(gg << 2) + m][nt], 0, 0, 0);
        }
    }

    // epilogue 2: silu + j-sum, butterfly across quads, store
    float b2v[2];
    #pragma unroll
    for (int nt = 0; nt < 2; ++nt) b2v[nt] = b2[(w << 5) + (nt << 4) + c];

    float s[2] = {0.f, 0.f};
    #pragma unroll
    for (int nt = 0; nt < 2; ++nt)
        #pragma unroll
        for (int mt = 0; mt < 8; ++mt)
            #pragma unroll
            for (int r = 0; r < 4; ++r)
                s[nt] += fast_silu(acc2[mt][nt][r] + b2v[nt]);

    #pragma unroll
    for (int nt = 0; nt < 2; ++nt) {
        s[nt] += __shfl_xor(s[nt], 16);
        s[nt] += __shfl_xor(s[nt], 32);
    }
    if (q < 2)
        out[((size_t)bi << 8) + (w << 5) + (q << 4) + c] = s[q] * 0.0078125f;
}

// ---------------------------------------------------------------------------
extern "C" void kernel_launch(void* const* d_in, const int* in_sizes, int n_in,
                              void* d_out, int out_size, void* d_ws, size_t ws_size,
                              hipStream_t stream)
{
    const float* node  = (const float*)d_in[0];
    const float* edge  = (const float*)d_in[1];
    const float* graph = (const float*)d_in[2];
    const float* W1    = (const float*)d_in[3];
    const float* b1    = (const float*)d_in[4];
    const float* W2    = (const float*)d_in[5];
    const float* b2    = (const float*)d_in[6];
    float* out = (float*)d_out;

    char* ws = (char*)d_ws;
    unsigned short* W2T   = (unsigned short*)ws;               // 131072 B
    unsigned short* WeT   = (unsigned short*)(ws + 131072);    //  32768 B
    unsigned short* W1jiT = (unsigned short*)(ws + 163840);    // 262144 B
    float* pg   = (float*)(ws + 425984);                       //  16384 B
    float* pj   = (float*)(ws + 442368);                       // 2 MB
    float* base = (float*)(ws + 442368 + 2097152);             // 2 MB

    pre_w          <<<784, 256, 0, stream>>>(W1, W2, graph, b1, W2T, WeT, W1jiT, pg);
    pre_pjbase_mfma<<< 64, 256, 0, stream>>>(node, W1jiT, pg, pj, base);
    fused_msg      <<<BSZ * NN, 512, 0, stream>>>(edge, pj, base, W2T, WeT, b2, out);
}